// Round 1
// baseline (395.934 us; speedup 1.0000x reference)
//
#include <hip/hip_runtime.h>
#include <hip/hip_bf16.h>

#define B_ 8
#define S_ 2048
#define H_ 4096
#define D_ 128
#define NS_ 128
#define KSPLIT 8
#define KC (H_ / KSPLIT) /* 512 */

// ---------------------------------------------------------------------------
// Workspace layout (float units):
//   idx     : int[B_*NS_]                       @ 0        (1024)
//   WkT     : float[H_][D_]                     @ 1024     (524288)
//   WqT     : float[H_][D_]                     @ 525312   (524288)
//   k_part  : float[KSPLIT][B_][NS_][D_]        @ 1049600  (1048576)
//   q_part  : float[KSPLIT][B_][D_]             @ 2098176  (8192)
//   v_part  : float[KSPLIT][B_][NS_]            @ 2106368  (8192)
// total ~8.5 MB. No zero-init required: every element is written before read.
// ---------------------------------------------------------------------------

// Kernel 1: transpose Wk,Wq ([D,H] -> [H,D]) and extract per-row indices of
// mask==1 in increasing order (== argsort(1-mask)[:NS] stable).
__global__ __launch_bounds__(256) void prep_kernel(
    const float* __restrict__ Wk, const float* __restrict__ Wq,
    const int* __restrict__ mask,
    float* __restrict__ WkT, float* __restrict__ WqT, int* __restrict__ idx)
{
    int bid = blockIdx.x;
    if (bid < 1024) {
        // 32x32 tiled transpose. 512 tiles per matrix.
        int m  = bid >> 9;          // 0 = Wk, 1 = Wq
        int t  = bid & 511;
        int ht = t & 127;           // h-tile (H/32 = 128)
        int dt = t >> 7;            // d-tile (D/32 = 4)
        const float* src = m ? Wq : Wk;
        float* dst = m ? WqT : WkT;
        __shared__ float tile[32][33];
        int tx = threadIdx.x & 31, ty = threadIdx.x >> 5;  // ty in 0..7
        #pragma unroll
        for (int j = 0; j < 4; ++j) {
            int d = dt * 32 + ty + j * 8;
            int h = ht * 32 + tx;
            tile[ty + j * 8][tx] = src[d * H_ + h];
        }
        __syncthreads();
        #pragma unroll
        for (int j = 0; j < 4; ++j) {
            int h = ht * 32 + ty + j * 8;
            int d = dt * 32 + tx;
            dst[h * D_ + d] = tile[tx][ty + j * 8];
        }
    } else {
        int b = bid - 1024;
        if (b >= B_) return;
        const int* mrow = mask + b * S_;
        __shared__ int wsum[4];
        int tid = threadIdx.x;
        int lane = tid & 63, wave = tid >> 6;
        int base = 0;
        for (int c = 0; c < S_ / 256; ++c) {
            int s = c * 256 + tid;
            int mv = mrow[s];
            unsigned long long bal = __ballot(mv != 0);
            int pre = __popcll(bal & ((1ull << lane) - 1ull));
            __syncthreads();                 // protect wsum from prev iter
            if (lane == 0) wsum[wave] = __popcll(bal);
            __syncthreads();
            int woff = 0, tot = 0;
            #pragma unroll
            for (int w = 0; w < 4; ++w) { if (w < wave) woff += wsum[w]; tot += wsum[w]; }
            if (mv) idx[b * NS_ + base + woff + pre] = s;
            base += tot;
        }
    }
}

// Kernel 2: gathered K-projection GEMM, split-K, + folded v-projection.
// Tile: 32 tokens x 128 d. Grid: b(8) x ttile(4) x kc(8) = 256 blocks.
__global__ __launch_bounds__(256) void kgemm_kernel(
    const float* __restrict__ hs, const float* __restrict__ WkT,
    const float* __restrict__ Wr, const int* __restrict__ idx,
    float* __restrict__ k_part, float* __restrict__ v_part)
{
    int bid = blockIdx.x;
    int b  = bid >> 5;
    int tt = (bid >> 3) & 3;
    int kc = bid & 7;
    int tid = threadIdx.x;

    __shared__ int idx_sh[32];
    __shared__ float Ash[64][34];       // [h][token], padded
    __shared__ float Bsh[64 * D_];      // [h][d]

    if (tid < 32) idx_sh[tid] = idx[b * NS_ + tt * 32 + tid];
    __syncthreads();

    // A-staging map: token at = tid/8, h-group ahg = tid%8 (8 floats each)
    int at  = tid >> 3;
    int ahg = tid & 7;
    const float* arow = hs + ((size_t)(b * S_ + idx_sh[at])) * H_ + kc * KC + ahg * 8;
    const float* wr   = Wr + kc * KC + ahg * 8;

    // compute map: 2 tokens x 8 d per thread
    int dg = tid & 15;  int d0 = dg * 8;
    int tg = tid >> 4;  int t0 = tg * 2;

    float acc[2][8];
    #pragma unroll
    for (int j = 0; j < 2; ++j)
        #pragma unroll
        for (int i = 0; i < 8; ++i) acc[j][i] = 0.f;
    float vacc = 0.f;

    for (int sub = 0; sub < KC / 64; ++sub) {
        // stage A (+ v partial from the already-loaded registers)
        float4 a0 = *(const float4*)(arow + sub * 64);
        float4 a1 = *(const float4*)(arow + sub * 64 + 4);
        float4 w0 = *(const float4*)(wr + sub * 64);
        float4 w1 = *(const float4*)(wr + sub * 64 + 4);
        vacc += a0.x * w0.x + a0.y * w0.y + a0.z * w0.z + a0.w * w0.w
              + a1.x * w1.x + a1.y * w1.y + a1.z * w1.z + a1.w * w1.w;
        Ash[ahg * 8 + 0][at] = a0.x; Ash[ahg * 8 + 1][at] = a0.y;
        Ash[ahg * 8 + 2][at] = a0.z; Ash[ahg * 8 + 3][at] = a0.w;
        Ash[ahg * 8 + 4][at] = a1.x; Ash[ahg * 8 + 5][at] = a1.y;
        Ash[ahg * 8 + 6][at] = a1.z; Ash[ahg * 8 + 7][at] = a1.w;
        // stage B: 64 h rows x 128 d, contiguous from WkT
        const float4* bsrc = (const float4*)(WkT + (size_t)(kc * KC + sub * 64) * D_);
        float4* bdst = (float4*)Bsh;
        #pragma unroll
        for (int i = 0; i < 8; ++i) bdst[i * 256 + tid] = bsrc[i * 256 + tid];
        __syncthreads();

        #pragma unroll 8
        for (int hh = 0; hh < 64; ++hh) {
            float a0v = Ash[hh][t0];
            float a1v = Ash[hh][t0 + 1];
            const float* brow = &Bsh[hh * D_ + d0];
            float4 b0 = *(const float4*)(brow);
            float4 b1 = *(const float4*)(brow + 4);
            acc[0][0] += a0v * b0.x; acc[0][1] += a0v * b0.y;
            acc[0][2] += a0v * b0.z; acc[0][3] += a0v * b0.w;
            acc[0][4] += a0v * b1.x; acc[0][5] += a0v * b1.y;
            acc[0][6] += a0v * b1.z; acc[0][7] += a0v * b1.w;
            acc[1][0] += a1v * b0.x; acc[1][1] += a1v * b0.y;
            acc[1][2] += a1v * b0.z; acc[1][3] += a1v * b0.w;
            acc[1][4] += a1v * b1.x; acc[1][5] += a1v * b1.y;
            acc[1][6] += a1v * b1.z; acc[1][7] += a1v * b1.w;
        }
        __syncthreads();
    }

    // epilogue: write per-kc partial tile (coalesced float4)
    float* kp = k_part + ((size_t)(kc * B_ + b) * NS_ + tt * 32) * D_;
    #pragma unroll
    for (int j = 0; j < 2; ++j) {
        float4 o0 = make_float4(acc[j][0], acc[j][1], acc[j][2], acc[j][3]);
        float4 o1 = make_float4(acc[j][4], acc[j][5], acc[j][6], acc[j][7]);
        *(float4*)(kp + (t0 + j) * D_ + d0)     = o0;
        *(float4*)(kp + (t0 + j) * D_ + d0 + 4) = o1;
    }

    // v: reduce the 8 h-group partials per token through LDS (reuse Ash)
    float* vsh = (float*)Ash;
    vsh[at * 8 + ahg] = vacc;
    __syncthreads();
    if (tid < 32) {
        float s = 0.f;
        #pragma unroll
        for (int i = 0; i < 8; ++i) s += vsh[tid * 8 + i];
        v_part[(kc * B_ + b) * NS_ + tt * 32 + tid] = s;
    }
}

// Kernel 3: q projection for the single last selected token per row, split-K.
__global__ __launch_bounds__(256) void qproj_kernel(
    const float* __restrict__ hs, const float* __restrict__ WqT,
    const int* __restrict__ idx, float* __restrict__ q_part)
{
    int b  = blockIdx.x >> 3;
    int kc = blockIdx.x & 7;
    int tid = threadIdx.x;
    int d = tid & 127, half = tid >> 7;
    int ilast = idx[b * NS_ + NS_ - 1];
    const float* row = hs + ((size_t)(b * S_ + ilast)) * H_ + kc * KC + half * 256;
    const float* wq  = WqT + (size_t)(kc * KC + half * 256) * D_ + d;
    float acc = 0.f;
    #pragma unroll 4
    for (int h = 0; h < 256; ++h) acc += row[h] * wq[h * D_];
    __shared__ float qsh[128];
    if (half == 1) qsh[d] = acc;
    __syncthreads();
    if (half == 0) q_part[(kc * B_ + b) * D_ + d] = acc + qsh[d];
}

// Kernel 4: reduce partials, biases, RoPE, logits, softmax, diff(v), outputs.
// Grid: 8 blocks (one per batch row), 128 threads (thread = token / d-index).
__global__ __launch_bounds__(128) void final_kernel(
    const float* __restrict__ k_part, const float* __restrict__ q_part,
    const float* __restrict__ v_part,
    const float* __restrict__ bq, const float* __restrict__ bk,
    const float* __restrict__ br, float* __restrict__ out)
{
    int b = blockIdx.x;
    int t = threadIdx.x;   // 0..127
    __shared__ float red[128];
    __shared__ float qr[128];
    __shared__ float vsh[128];

    // q = sum_kc q_part + bq
    float q = bq[t];
    #pragma unroll
    for (int kc = 0; kc < KSPLIT; ++kc) q += q_part[(kc * B_ + b) * D_ + t];
    red[t] = q;
    __syncthreads();                                   // (1)

    // RoPE on q with sentence position NS-1 = 127
    {
        int i = t >> 1;
        float fr = 1.0f / powf(10000.0f, (float)(2 * i) / 128.0f);
        float ang = 127.0f * fr;
        float s, c; sincosf(ang, &s, &c);
        float x0 = red[2 * i], x1 = red[2 * i + 1];
        qr[t] = (t & 1) ? (x0 * s + x1 * c) : (x0 * c - x1 * s);
    }

    // v = sum_kc v_part + br ; sr = first-difference
    float v = br[0];
    #pragma unroll
    for (int kc = 0; kc < KSPLIT; ++kc) v += v_part[(kc * B_ + b) * NS_ + t];
    vsh[t] = v;
    __syncthreads();                                   // (2) qr+vsh visible
    float sr = (t == 0) ? vsh[0] : vsh[t] - vsh[t - 1];

    // k row t: sum partials, bias, RoPE(pos=t), dot with roped q
    float logit = 0.f;
    #pragma unroll 4
    for (int i = 0; i < 32; ++i) {           // i indexes float4 = 2 rope pairs
        float4 kv = make_float4(0.f, 0.f, 0.f, 0.f);
        #pragma unroll
        for (int kc = 0; kc < KSPLIT; ++kc) {
            float4 x = ((const float4*)(k_part + ((size_t)(kc * B_ + b) * NS_ + t) * D_))[i];
            kv.x += x.x; kv.y += x.y; kv.z += x.z; kv.w += x.w;
        }
        kv.x += bk[4 * i + 0]; kv.y += bk[4 * i + 1];
        kv.z += bk[4 * i + 2]; kv.w += bk[4 * i + 3];
        int j0 = 2 * i;
        float fr0 = 1.0f / powf(10000.0f, (float)(2 * j0) / 128.0f);
        float fr1 = 1.0f / powf(10000.0f, (float)(2 * (j0 + 1)) / 128.0f);
        float s0, c0, s1, c1;
        sincosf((float)t * fr0, &s0, &c0);
        sincosf((float)t * fr1, &s1, &c1);
        float k0 = kv.x * c0 - kv.y * s0;
        float k1 = kv.x * s0 + kv.y * c0;
        float k2 = kv.z * c1 - kv.w * s1;
        float k3 = kv.z * s1 + kv.w * c1;
        logit += k0 * qr[4 * i] + k1 * qr[4 * i + 1] + k2 * qr[4 * i + 2] + k3 * qr[4 * i + 3];
    }
    logit *= 0.08838834764831845f;   // 1/sqrt(128)

    red[t] = logit;
    __syncthreads();                                   // (3)
    // max-reduce over 128
    #pragma unroll
    for (int off = 64; off > 0; off >>= 1) {
        if (t < off) red[t] = fmaxf(red[t], red[t + off]);
        __syncthreads();
    }
    float mx = red[0];
    float e = expf(logit - mx);
    vsh[t] = e;          // sr already in registers; safe to reuse vsh
    __syncthreads();
    #pragma unroll
    for (int off = 64; off > 0; off >>= 1) {
        if (t < off) vsh[t] += vsh[t + off];
        __syncthreads();
    }
    float attn = e / vsh[0];

    out[b * NS_ + t] = sr * attn;                      // sentence_rewards

    red[t] = attn * sr;
    __syncthreads();
    #pragma unroll
    for (int off = 64; off > 0; off >>= 1) {
        if (t < off) red[t] += red[t + off];
        __syncthreads();
    }
    if (t == 0) out[B_ * NS_ + b] = red[0];            // sequence_rewards
}

extern "C" void kernel_launch(void* const* d_in, const int* in_sizes, int n_in,
                              void* d_out, int out_size, void* d_ws, size_t ws_size,
                              hipStream_t stream) {
    const float* hs   = (const float*)d_in[0];
    const int*   mask = (const int*)d_in[1];
    // d_in[2] = num_sentences (128, hardcoded)
    const float* Wq = (const float*)d_in[3];
    const float* bq = (const float*)d_in[4];
    const float* Wk = (const float*)d_in[5];
    const float* bk = (const float*)d_in[6];
    const float* Wr = (const float*)d_in[7];
    const float* br = (const float*)d_in[8];
    float* out = (float*)d_out;

    float* ws = (float*)d_ws;
    int*   idx    = (int*)ws;
    float* WkT    = ws + 1024;
    float* WqT    = WkT + (size_t)H_ * D_;
    float* k_part = WqT + (size_t)H_ * D_;
    float* q_part = k_part + (size_t)KSPLIT * B_ * NS_ * D_;
    float* v_part = q_part + (size_t)KSPLIT * B_ * D_;

    prep_kernel <<<1032, 256, 0, stream>>>(Wk, Wq, mask, WkT, WqT, idx);
    kgemm_kernel<<<256,  256, 0, stream>>>(hs, WkT, Wr, idx, k_part, v_part);
    qproj_kernel<<<64,   256, 0, stream>>>(hs, WqT, idx, q_part);
    final_kernel<<<8,    128, 0, stream>>>(k_part, q_part, v_part, bq, bk, br, out);
}

// Round 2
// 349.198 us; speedup vs baseline: 1.1338x; 1.1338x over previous
//
#include <hip/hip_runtime.h>
#include <hip/hip_bf16.h>

#define B_ 8
#define S_ 2048
#define H_ 4096
#define D_ 128
#define NS_ 128
#define KS 32            /* split-K for kgemm */
#define KC (H_ / KS)     /* 128 */
#define KSQ 8            /* split-K for qproj */
#define KCQ (H_ / KSQ)   /* 512 */

// ---------------------------------------------------------------------------
// Workspace layout (float units):
//   idx     : int[1024]                    @ 0
//   WkT     : float[H][D]                  @ 1024      (524288)
//   WqT     : float[H][D]                  @ 525312    (524288)
//   k_part  : float[KS][B][NS][D]          @ 1049600   (4194304)
//   q_part  : float[KSQ][B][D]             @ 5243904   (8192)
//   v_part  : float[KS][B][NS]             @ 5252096   (32768)
//   logits  : float[B][NS]                 @ 5284864   (1024)
//   v_red   : float[B][NS]                 @ 5285888   (1024)
// total ~21.1 MB; every element written before read (ws is poisoned 0xAA).
// ---------------------------------------------------------------------------

// Kernel 1: transpose Wk,Wq ([D,H]->[H,D]); extract sorted indices of mask==1.
__global__ __launch_bounds__(256) void prep_kernel(
    const float* __restrict__ Wk, const float* __restrict__ Wq,
    const int* __restrict__ mask,
    float* __restrict__ WkT, float* __restrict__ WqT, int* __restrict__ idx)
{
    int bid = blockIdx.x;
    if (bid < 1024) {
        int m  = bid >> 9;
        int t  = bid & 511;
        int ht = t & 127;
        int dt = t >> 7;
        const float* src = m ? Wq : Wk;
        float* dst = m ? WqT : WkT;
        __shared__ float tile[32][33];
        int tx = threadIdx.x & 31, ty = threadIdx.x >> 5;
        #pragma unroll
        for (int j = 0; j < 4; ++j)
            tile[ty + j * 8][tx] = src[(dt * 32 + ty + j * 8) * H_ + ht * 32 + tx];
        __syncthreads();
        #pragma unroll
        for (int j = 0; j < 4; ++j)
            dst[(ht * 32 + ty + j * 8) * D_ + dt * 32 + tx] = tile[tx][ty + j * 8];
    } else {
        int b = bid - 1024;
        if (b >= B_) return;
        const int* mrow = mask + b * S_;
        __shared__ int wsum[4];
        int tid = threadIdx.x;
        int lane = tid & 63, wave = tid >> 6;
        int base = 0;
        for (int c = 0; c < S_ / 256; ++c) {
            int s = c * 256 + tid;
            int mv = mrow[s];
            unsigned long long bal = __ballot(mv != 0);
            int pre = __popcll(bal & ((1ull << lane) - 1ull));
            __syncthreads();
            if (lane == 0) wsum[wave] = __popcll(bal);
            __syncthreads();
            int woff = 0, tot = 0;
            #pragma unroll
            for (int w = 0; w < 4; ++w) { if (w < wave) woff += wsum[w]; tot += wsum[w]; }
            if (mv) idx[b * NS_ + base + woff + pre] = s;
            base += tot;
        }
    }
}

// Kernel 2: blocks 0..255: gathered K-GEMM (tile 128 tok x 128 d, split-K 32)
//           + folded v-projection. Blocks 256..319: q GEMV (split-K 8).
__global__ __launch_bounds__(256) void kgemm_kernel(
    const float* __restrict__ hs, const float* __restrict__ WkT,
    const float* __restrict__ WqT, const float* __restrict__ Wr,
    const int* __restrict__ idx,
    float* __restrict__ k_part, float* __restrict__ v_part,
    float* __restrict__ q_part)
{
    __shared__ char smem[65536];                 // exactly 64 KB, all aliased
    float (*Ash)[NS_] = (float (*)[NS_])smem;            // [64 h][128 tok]
    float (*Bsh)[D_]  = (float (*)[D_])(smem + 32768);   // [64 h][128 d]
    int tid = threadIdx.x;
    int bid = blockIdx.x;

    if (bid >= 256) {
        // ---- q projection for the last selected token per row ----
        int qb = bid - 256;
        int b  = qb >> 3;
        int kc = qb & 7;
        float* qsh = (float*)smem;
        int d = tid & 127, half = tid >> 7;
        int ilast = idx[b * NS_ + NS_ - 1];
        const float* row = hs + ((size_t)(b * S_ + ilast)) * H_ + kc * KCQ + half * 256;
        const float* wq  = WqT + (size_t)(kc * KCQ + half * 256) * D_ + d;
        float acc = 0.f;
        #pragma unroll 4
        for (int h = 0; h < 256; ++h) acc += row[h] * wq[h * (size_t)D_];
        if (half == 1) qsh[d] = acc;
        __syncthreads();
        if (half == 0) q_part[(kc * B_ + b) * D_ + d] = acc + qsh[d];
        return;
    }

    int b  = bid >> 5;      // 0..7
    int kc = bid & 31;      // 0..31

    // load indices into (aliased) LDS, read them, then barrier before Bsh use
    int* idx_sh = (int*)(smem + 32768);
    if (tid < 128) idx_sh[tid] = idx[b * NS_ + tid];
    __syncthreads();
    int at = tid & 127, ahalf = tid >> 7;
    const float* arow = hs + ((size_t)(b * S_ + idx_sh[at])) * H_ + kc * KC + ahalf * 32;
    __syncthreads();        // everyone done reading idx_sh before Bsh writes

    const float* wr = Wr + kc * KC + ahalf * 32;
    int dg = tid & 15, tg = tid >> 4;
    int d0 = dg * 8, t0 = tg * 8;

    float acc[8][8];
    #pragma unroll
    for (int i = 0; i < 8; ++i)
        #pragma unroll
        for (int j = 0; j < 8; ++j) acc[i][j] = 0.f;
    float vacc = 0.f;

    const float* bsrc = WkT + (size_t)(kc * KC) * D_;

    #pragma unroll
    for (int sub = 0; sub < 2; ++sub) {
        // --- stage A: 128 tok x 64 h, each thread 32 consecutive floats ---
        float4 av[8];
        #pragma unroll
        for (int i = 0; i < 8; ++i) av[i] = *(const float4*)(arow + sub * 64 + i * 4);
        #pragma unroll
        for (int i = 0; i < 8; ++i) {
            float4 w = *(const float4*)(wr + sub * 64 + i * 4);
            vacc += av[i].x * w.x + av[i].y * w.y + av[i].z * w.z + av[i].w * w.w;
        }
        #pragma unroll
        for (int i = 0; i < 8; ++i) {
            int h = ahalf * 32 + i * 4;
            Ash[h + 0][at] = av[i].x; Ash[h + 1][at] = av[i].y;
            Ash[h + 2][at] = av[i].z; Ash[h + 3][at] = av[i].w;
        }
        // --- stage B: 64 h x 128 d contiguous copy (2048 float4) ---
        const float4* bs4 = (const float4*)(bsrc + (size_t)sub * 64 * D_);
        float4* bd4 = (float4*)&Bsh[0][0];
        #pragma unroll
        for (int i = 0; i < 8; ++i) bd4[i * 256 + tid] = bs4[i * 256 + tid];
        __syncthreads();

        // --- compute: per-thread 8 tok x 8 d, 64 FMA per hh ---
        #pragma unroll 4
        for (int hh = 0; hh < 64; ++hh) {
            float a[8], bb[8];
            *(float4*)&a[0]  = *(const float4*)&Ash[hh][t0];
            *(float4*)&a[4]  = *(const float4*)&Ash[hh][t0 + 4];
            *(float4*)&bb[0] = *(const float4*)&Bsh[hh][d0];
            *(float4*)&bb[4] = *(const float4*)&Bsh[hh][d0 + 4];
            #pragma unroll
            for (int i = 0; i < 8; ++i)
                #pragma unroll
                for (int j = 0; j < 8; ++j)
                    acc[i][j] += a[i] * bb[j];
        }
        __syncthreads();
    }

    // epilogue: write per-kc partial tile
    float* kp = k_part + (size_t)(kc * B_ + b) * NS_ * D_;
    #pragma unroll
    for (int i = 0; i < 8; ++i) {
        *(float4*)(kp + (t0 + i) * D_ + d0)     = make_float4(acc[i][0], acc[i][1], acc[i][2], acc[i][3]);
        *(float4*)(kp + (t0 + i) * D_ + d0 + 4) = make_float4(acc[i][4], acc[i][5], acc[i][6], acc[i][7]);
    }

    // v reduce (overlay onto smem — all compute is past the last barrier)
    float* vsh = (float*)smem;
    vsh[at * 2 + ahalf] = vacc;
    __syncthreads();
    if (tid < 128) v_part[(kc * B_ + b) * NS_ + tid] = vsh[tid * 2] + vsh[tid * 2 + 1];
}

// Kernel 3: per (b, 8-token chunk): reduce q/k/v partials, RoPE, logits.
__global__ __launch_bounds__(256) void logit_kernel(
    const float* __restrict__ k_part, const float* __restrict__ q_part,
    const float* __restrict__ v_part,
    const float* __restrict__ bq, const float* __restrict__ bk,
    const float* __restrict__ br,
    float* __restrict__ logits, float* __restrict__ v_red)
{
    int b  = blockIdx.x >> 4;
    int tc = blockIdx.x & 15;
    int tid = threadIdx.x;
    __shared__ float qtmp[2][D_];
    __shared__ float qr[D_];
    __shared__ float lred[8][32];

    // 1. q = sum_kc q_part + bq  (split the 8 kc's across the two halves)
    {
        int d = tid & 127, hf = tid >> 7;
        float qv = hf ? 0.f : bq[d];
        #pragma unroll
        for (int kc = 0; kc < 4; ++kc) qv += q_part[((hf * 4 + kc) * B_ + b) * D_ + d];
        qtmp[hf][d] = qv;
    }
    // v partial for this block's tokens: thread = (tok=tid>>5, kc=tid&31)
    int vt = tid >> 5, vkc = tid & 31;
    float vv = v_part[(vkc * B_ + b) * NS_ + tc * 8 + vt];
    __syncthreads();                                    // s1

    // 2. RoPE(q, pos=127)
    if (tid < 128) {
        int i = tid >> 1;
        float x0 = qtmp[0][2 * i] + qtmp[1][2 * i];
        float x1 = qtmp[0][2 * i + 1] + qtmp[1][2 * i + 1];
        float fr = 1.0f / powf(10000.0f, (float)(2 * i) / 128.0f);
        float s, c; sincosf(127.0f * fr, &s, &c);
        qr[tid] = (tid & 1) ? (x0 * s + x1 * c) : (x0 * c - x1 * s);
    }
    lred[vt][vkc] = vv;
    __syncthreads();                                    // s2
    if (tid < 8) {
        float s = br[0];
        #pragma unroll
        for (int j = 0; j < 32; ++j) s += lred[tid][j];
        v_red[b * NS_ + tc * 8 + tid] = s;
    }

    // 3. k reduce + bias + RoPE(pos=token) + dot with roped q
    int tok = tid >> 5, q4 = tid & 31;
    int tg  = tc * 8 + tok;
    float4 kv = make_float4(0.f, 0.f, 0.f, 0.f);
    #pragma unroll 8
    for (int kc = 0; kc < KS; ++kc) {
        float4 x = *(const float4*)(k_part + ((size_t)(kc * B_ + b) * NS_ + tg) * D_ + q4 * 4);
        kv.x += x.x; kv.y += x.y; kv.z += x.z; kv.w += x.w;
    }
    kv.x += bk[4 * q4 + 0]; kv.y += bk[4 * q4 + 1];
    kv.z += bk[4 * q4 + 2]; kv.w += bk[4 * q4 + 3];
    float fr0 = 1.0f / powf(10000.0f, (float)(4 * q4) / 128.0f);
    float fr1 = 1.0f / powf(10000.0f, (float)(4 * q4 + 2) / 128.0f);
    float s0, c0, s1, c1;
    sincosf((float)tg * fr0, &s0, &c0);
    sincosf((float)tg * fr1, &s1, &c1);
    float k0 = kv.x * c0 - kv.y * s0;
    float k1 = kv.x * s0 + kv.y * c0;
    float k2 = kv.z * c1 - kv.w * s1;
    float k3 = kv.z * s1 + kv.w * c1;
    float part = k0 * qr[4 * q4] + k1 * qr[4 * q4 + 1]
               + k2 * qr[4 * q4 + 2] + k3 * qr[4 * q4 + 3];
    __syncthreads();                                    // s3 (lred reads done)
    lred[tok][q4] = part;
    __syncthreads();                                    // s4
    if (tid < 8) {
        float s = 0.f;
        #pragma unroll
        for (int j = 0; j < 32; ++j) s += lred[tid][j];
        logits[b * NS_ + tc * 8 + tid] = s * 0.08838834764831845f;
    }
}

// Kernel 4: per-b softmax + first-difference + outputs.
__global__ __launch_bounds__(128) void softmax_kernel(
    const float* __restrict__ logits, const float* __restrict__ v_red,
    float* __restrict__ out)
{
    int b = blockIdx.x;
    int t = threadIdx.x;
    __shared__ float red[128];
    __shared__ float vsh[128];

    float logit = logits[b * NS_ + t];
    vsh[t] = v_red[b * NS_ + t];
    red[t] = logit;
    __syncthreads();
    float sr = (t == 0) ? vsh[0] : vsh[t] - vsh[t - 1];
    #pragma unroll
    for (int off = 64; off > 0; off >>= 1) {
        if (t < off) red[t] = fmaxf(red[t], red[t + off]);
        __syncthreads();
    }
    float mx = red[0];
    __syncthreads();
    float e = expf(logit - mx);
    red[t] = e;
    __syncthreads();
    #pragma unroll
    for (int off = 64; off > 0; off >>= 1) {
        if (t < off) red[t] += red[t + off];
        __syncthreads();
    }
    float attn = e / red[0];
    out[b * NS_ + t] = sr * attn;
    __syncthreads();
    red[t] = attn * sr;
    __syncthreads();
    #pragma unroll
    for (int off = 64; off > 0; off >>= 1) {
        if (t < off) red[t] += red[t + off];
        __syncthreads();
    }
    if (t == 0) out[B_ * NS_ + b] = red[0];
}

extern "C" void kernel_launch(void* const* d_in, const int* in_sizes, int n_in,
                              void* d_out, int out_size, void* d_ws, size_t ws_size,
                              hipStream_t stream) {
    const float* hs   = (const float*)d_in[0];
    const int*   mask = (const int*)d_in[1];
    const float* Wq = (const float*)d_in[3];
    const float* bq = (const float*)d_in[4];
    const float* Wk = (const float*)d_in[5];
    const float* bk = (const float*)d_in[6];
    const float* Wr = (const float*)d_in[7];
    const float* br = (const float*)d_in[8];
    float* out = (float*)d_out;

    float* ws = (float*)d_ws;
    int*   idx    = (int*)ws;
    float* WkT    = ws + 1024;
    float* WqT    = WkT + (size_t)H_ * D_;
    float* k_part = WqT + (size_t)H_ * D_;
    float* q_part = k_part + (size_t)KS * B_ * NS_ * D_;
    float* v_part = q_part + (size_t)KSQ * B_ * D_;
    float* logits = v_part + (size_t)KS * B_ * NS_;
    float* v_red  = logits + B_ * NS_;

    prep_kernel   <<<1032, 256, 0, stream>>>(Wk, Wq, mask, WkT, WqT, idx);
    kgemm_kernel  <<<320,  256, 0, stream>>>(hs, WkT, WqT, Wr, idx, k_part, v_part, q_part);
    logit_kernel  <<<128,  256, 0, stream>>>(k_part, q_part, v_part, bq, bk, br, logits, v_red);
    softmax_kernel<<<8,    128, 0, stream>>>(logits, v_red, out);
}

// Round 3
// 341.507 us; speedup vs baseline: 1.1594x; 1.0225x over previous
//
#include <hip/hip_runtime.h>
#include <hip/hip_bf16.h>

#define B_ 8
#define S_ 2048
#define H_ 4096
#define D_ 128
#define NS_ 128
#define KS 32            /* split-K for kgemm: KC = 128 h per block */
#define KC (H_ / KS)
#define KSQ 8            /* split-K for qproj: 512 h per block */

typedef _Float16 half8 __attribute__((ext_vector_type(8)));
typedef float floatx4 __attribute__((ext_vector_type(4)));

// ---------------------------------------------------------------------------
// Workspace (float units):
//   idx     : int[1024]            @ 0
//   k_part  : float[KS][B][NS][D]  @ 1024      (4194304)
//   q_part  : float[KSQ][B][D]     @ 4195328   (8192)
//   v_part  : float[KS][B][NS]     @ 4203520   (32768)
//   logits  : float[B][NS]         @ 4236288   (1024)
//   v_red   : float[B][NS]         @ 4237312   (1024)
// every element written before read (ws poisoned 0xAA).
// ---------------------------------------------------------------------------

__device__ inline void cvt8(const float* x, half8* hi, half8* lo) {
    half8 h, l;
    #pragma unroll
    for (int j = 0; j < 8; ++j) {
        _Float16 hh = (_Float16)x[j];
        h[j] = hh;
        l[j] = (_Float16)(x[j] - (float)hh);
    }
    *hi = h; *lo = l;
}

__device__ inline floatx4 mfma16(half8 a, half8 b, floatx4 c) {
    return __builtin_amdgcn_mfma_f32_16x16x32_f16(a, b, c, 0, 0, 0);
}

// Kernel 1: extract per-row sorted positions of mask==1 (8 blocks).
__global__ __launch_bounds__(256) void prep_kernel(
    const int* __restrict__ mask, int* __restrict__ idx)
{
    int b = blockIdx.x;
    const int* mrow = mask + b * S_;
    __shared__ int wsum[4];
    int tid = threadIdx.x;
    int lane = tid & 63, wave = tid >> 6;
    int base = 0;
    for (int c = 0; c < S_ / 256; ++c) {
        int s = c * 256 + tid;
        int mv = mrow[s];
        unsigned long long bal = __ballot(mv != 0);
        int pre = __popcll(bal & ((1ull << lane) - 1ull));
        __syncthreads();
        if (lane == 0) wsum[wave] = __popcll(bal);
        __syncthreads();
        int woff = 0, tot = 0;
        #pragma unroll
        for (int w = 0; w < 4; ++w) { if (w < wave) woff += wsum[w]; tot += wsum[w]; }
        if (mv) idx[b * NS_ + base + woff + pre] = s;
        base += tot;
    }
}

// Kernel 2: blocks 0..255: gathered K-projection via f16x3 MFMA, split-K 32,
//           + exact-fp32 v-projection folded into A staging.
//           Blocks 256..319: q GEMV (split-K 8) reading Wq rows directly.
// MFMA 16x16x32 f16 layouts (shape-determined, m89/m121-verified):
//   A-frag: lane holds A[m=lane&15][k=(lane>>4)*8+j]      (A = tokens x h)
//   B-frag: lane holds B^T[n=lane&15][k=(lane>>4)*8+j]    (B^T = Wk[d][h] !)
//   C/D   : col(n)=lane&15, row(m)=(lane>>4)*4+reg
__global__ __launch_bounds__(256) void kgemm_kernel(
    const float* __restrict__ hs, const float* __restrict__ Wk,
    const float* __restrict__ Wq, const float* __restrict__ Wr,
    const int* __restrict__ idx,
    float* __restrict__ k_part, float* __restrict__ v_part,
    float* __restrict__ q_part)
{
    __shared__ __align__(16) char smem[65536];
    int tid = threadIdx.x;
    int bid = blockIdx.x;

    if (bid >= 256) {
        // ---- q projection for the last selected token ----
        int qb = bid - 256;
        int b  = qb >> 3;
        int kc = qb & 7;
        float* hsrow = (float*)smem;            // 2 KB
        float* qred  = (float*)(smem + 2048);   // 512 B
        int ilast = idx[b * NS_ + NS_ - 1];
        const float* rp = hs + ((size_t)(b * S_ + ilast)) * H_ + kc * 512;
        if (tid < 128) ((float4*)hsrow)[tid] = ((const float4*)rp)[tid];
        __syncthreads();
        int d = tid & 127, half = tid >> 7;
        const float* wq = Wq + (size_t)d * H_ + kc * 512 + half * 256;
        const float* hh = hsrow + half * 256;
        float acc = 0.f;
        #pragma unroll 8
        for (int h = 0; h < 256; h += 4) {
            float4 w = *(const float4*)(wq + h);
            acc += hh[h] * w.x + hh[h + 1] * w.y + hh[h + 2] * w.z + hh[h + 3] * w.w;
        }
        if (half) qred[d] = acc;
        __syncthreads();
        if (!half) q_part[(kc * B_ + b) * D_ + d] = acc + qred[d];
        return;
    }

    int b  = bid >> 5;      // 0..7
    int kc = bid & 31;      // 0..31

    half8* AhS = (half8*)smem;                  // [8 kg][128 tok] : 16 KB
    half8* AlS = (half8*)(smem + 16384);
    half8* BhS = (half8*)(smem + 32768);        // [8 kg][128 d]
    half8* BlS = (half8*)(smem + 49152);

    int ia   = tid & 127;        // tok for A-staging, d for B-staging
    int half = tid >> 7;         // h-half (32 floats each)
    int row  = idx[b * NS_ + ia];
    const float* ap  = hs + ((size_t)(b * S_ + row)) * H_ + kc * KC + half * 32;
    const float* bp  = Wk + (size_t)ia * H_ + kc * KC + half * 32;
    const float* wrp = Wr + kc * KC + half * 32;

    int lane = tid & 63, w = tid >> 6;
    int quad = lane >> 4, mrow = lane & 15;
    int TB = (w >> 1) * 64;      // wave token base
    int DB = (w & 1) * 64;       // wave d base

    floatx4 acc[4][4];
    #pragma unroll
    for (int i = 0; i < 4; ++i)
        #pragma unroll
        for (int j = 0; j < 4; ++j) acc[i][j] = (floatx4){0.f, 0.f, 0.f, 0.f};
    float vacc = 0.f;

    #pragma unroll
    for (int c = 0; c < 2; ++c) {               // two 64-h chunks
        // ---- stage A (hi/lo f16) + exact v partial ----
        #pragma unroll
        for (int g = 0; g < 4; ++g) {
            float x[8], wv[8];
            *(float4*)&x[0]  = *(const float4*)(ap + c * 64 + g * 8);
            *(float4*)&x[4]  = *(const float4*)(ap + c * 64 + g * 8 + 4);
            *(float4*)&wv[0] = *(const float4*)(wrp + c * 64 + g * 8);
            *(float4*)&wv[4] = *(const float4*)(wrp + c * 64 + g * 8 + 4);
            #pragma unroll
            for (int j = 0; j < 8; ++j) vacc += x[j] * wv[j];
            half8 hi, lo; cvt8(x, &hi, &lo);
            AhS[(half * 4 + g) * 128 + ia] = hi;
            AlS[(half * 4 + g) * 128 + ia] = lo;
        }
        // ---- stage B (hi/lo f16) from Wk rows (no transpose needed) ----
        #pragma unroll
        for (int g = 0; g < 4; ++g) {
            float x[8];
            *(float4*)&x[0] = *(const float4*)(bp + c * 64 + g * 8);
            *(float4*)&x[4] = *(const float4*)(bp + c * 64 + g * 8 + 4);
            half8 hi, lo; cvt8(x, &hi, &lo);
            BhS[(half * 4 + g) * 128 + ia] = hi;
            BlS[(half * 4 + g) * 128 + ia] = lo;
        }
        __syncthreads();

        // ---- MFMA: 2 k-steps x (16 frag loads -> 48 mfma) ----
        #pragma unroll
        for (int k0 = 0; k0 < 2; ++k0) {
            int kb = (k0 * 4 + quad) * 128;
            half8 ah[4], al[4], bh[4], bl[4];
            #pragma unroll
            for (int i = 0; i < 4; ++i) {
                ah[i] = AhS[kb + TB + i * 16 + mrow];
                al[i] = AlS[kb + TB + i * 16 + mrow];
                bh[i] = BhS[kb + DB + i * 16 + mrow];
                bl[i] = BlS[kb + DB + i * 16 + mrow];
            }
            #pragma unroll
            for (int mt = 0; mt < 4; ++mt)
                #pragma unroll
                for (int nt = 0; nt < 4; ++nt) {
                    acc[mt][nt] = mfma16(ah[mt], bh[nt], acc[mt][nt]);
                    acc[mt][nt] = mfma16(ah[mt], bl[nt], acc[mt][nt]);
                    acc[mt][nt] = mfma16(al[mt], bh[nt], acc[mt][nt]);
                }
        }
        __syncthreads();
    }

    // ---- epilogue: write k_part in [tok][d] layout per C/D mapping ----
    float* kp = k_part + (size_t)(kc * B_ + b) * NS_ * D_;
    #pragma unroll
    for (int mt = 0; mt < 4; ++mt)
        #pragma unroll
        for (int nt = 0; nt < 4; ++nt)
            #pragma unroll
            for (int r = 0; r < 4; ++r) {
                int tok = TB + mt * 16 + quad * 4 + r;
                int d   = DB + nt * 16 + mrow;
                kp[tok * D_ + d] = acc[mt][nt][r];
            }

    // ---- v reduce (reuse smem; all LDS frag reads are behind the barrier) --
    float* vb = (float*)smem;
    vb[half * 128 + ia] = vacc;
    __syncthreads();
    if (tid < 128) v_part[(kc * B_ + b) * NS_ + tid] = vb[tid] + vb[128 + tid];
}

// Kernel 3: per (b, 8-token chunk): reduce q/k/v partials, RoPE, logits.
__global__ __launch_bounds__(256) void logit_kernel(
    const float* __restrict__ k_part, const float* __restrict__ q_part,
    const float* __restrict__ v_part,
    const float* __restrict__ bq, const float* __restrict__ bk,
    const float* __restrict__ br,
    float* __restrict__ logits, float* __restrict__ v_red)
{
    int b  = blockIdx.x >> 4;
    int tc = blockIdx.x & 15;
    int tid = threadIdx.x;
    __shared__ float qtmp[2][D_];
    __shared__ float qr[D_];
    __shared__ float lred[8][32];

    {
        int d = tid & 127, hf = tid >> 7;
        float qv = hf ? 0.f : bq[d];
        #pragma unroll
        for (int kc = 0; kc < 4; ++kc) qv += q_part[((hf * 4 + kc) * B_ + b) * D_ + d];
        qtmp[hf][d] = qv;
    }
    int vt = tid >> 5, vkc = tid & 31;
    float vv = v_part[(vkc * B_ + b) * NS_ + tc * 8 + vt];
    __syncthreads();

    if (tid < 128) {
        int i = tid >> 1;
        float x0 = qtmp[0][2 * i] + qtmp[1][2 * i];
        float x1 = qtmp[0][2 * i + 1] + qtmp[1][2 * i + 1];
        float fr = 1.0f / powf(10000.0f, (float)(2 * i) / 128.0f);
        float s, c; sincosf(127.0f * fr, &s, &c);
        qr[tid] = (tid & 1) ? (x0 * s + x1 * c) : (x0 * c - x1 * s);
    }
    lred[vt][vkc] = vv;
    __syncthreads();
    if (tid < 8) {
        float s = br[0];
        #pragma unroll
        for (int j = 0; j < 32; ++j) s += lred[tid][j];
        v_red[b * NS_ + tc * 8 + tid] = s;
    }

    int tok = tid >> 5, q4 = tid & 31;
    int tg  = tc * 8 + tok;
    float4 kv = make_float4(0.f, 0.f, 0.f, 0.f);
    #pragma unroll 8
    for (int kc = 0; kc < KS; ++kc) {
        float4 x = *(const float4*)(k_part + ((size_t)(kc * B_ + b) * NS_ + tg) * D_ + q4 * 4);
        kv.x += x.x; kv.y += x.y; kv.z += x.z; kv.w += x.w;
    }
    kv.x += bk[4 * q4 + 0]; kv.y += bk[4 * q4 + 1];
    kv.z += bk[4 * q4 + 2]; kv.w += bk[4 * q4 + 3];
    float fr0 = 1.0f / powf(10000.0f, (float)(4 * q4) / 128.0f);
    float fr1 = 1.0f / powf(10000.0f, (float)(4 * q4 + 2) / 128.0f);
    float s0, c0, s1, c1;
    sincosf((float)tg * fr0, &s0, &c0);
    sincosf((float)tg * fr1, &s1, &c1);
    float k0 = kv.x * c0 - kv.y * s0;
    float k1 = kv.x * s0 + kv.y * c0;
    float k2 = kv.z * c1 - kv.w * s1;
    float k3 = kv.z * s1 + kv.w * c1;
    float part = k0 * qr[4 * q4] + k1 * qr[4 * q4 + 1]
               + k2 * qr[4 * q4 + 2] + k3 * qr[4 * q4 + 3];
    __syncthreads();
    lred[tok][q4] = part;
    __syncthreads();
    if (tid < 8) {
        float s = 0.f;
        #pragma unroll
        for (int j = 0; j < 32; ++j) s += lred[tid][j];
        logits[b * NS_ + tc * 8 + tid] = s * 0.08838834764831845f;
    }
}

// Kernel 4: per-b softmax + first-difference + outputs.
__global__ __launch_bounds__(128) void softmax_kernel(
    const float* __restrict__ logits, const float* __restrict__ v_red,
    float* __restrict__ out)
{
    int b = blockIdx.x;
    int t = threadIdx.x;
    __shared__ float red[128];
    __shared__ float vsh[128];

    float logit = logits[b * NS_ + t];
    vsh[t] = v_red[b * NS_ + t];
    red[t] = logit;
    __syncthreads();
    float sr = (t == 0) ? vsh[0] : vsh[t] - vsh[t - 1];
    #pragma unroll
    for (int off = 64; off > 0; off >>= 1) {
        if (t < off) red[t] = fmaxf(red[t], red[t + off]);
        __syncthreads();
    }
    float mx = red[0];
    __syncthreads();
    float e = expf(logit - mx);
    red[t] = e;
    __syncthreads();
    #pragma unroll
    for (int off = 64; off > 0; off >>= 1) {
        if (t < off) red[t] += red[t + off];
        __syncthreads();
    }
    float attn = e / red[0];
    out[b * NS_ + t] = sr * attn;
    __syncthreads();
    red[t] = attn * sr;
    __syncthreads();
    #pragma unroll
    for (int off = 64; off > 0; off >>= 1) {
        if (t < off) red[t] += red[t + off];
        __syncthreads();
    }
    if (t == 0) out[B_ * NS_ + b] = red[0];
}

extern "C" void kernel_launch(void* const* d_in, const int* in_sizes, int n_in,
                              void* d_out, int out_size, void* d_ws, size_t ws_size,
                              hipStream_t stream) {
    const float* hs   = (const float*)d_in[0];
    const int*   mask = (const int*)d_in[1];
    const float* Wq = (const float*)d_in[3];
    const float* bq = (const float*)d_in[4];
    const float* Wk = (const float*)d_in[5];
    const float* bk = (const float*)d_in[6];
    const float* Wr = (const float*)d_in[7];
    const float* br = (const float*)d_in[8];
    float* out = (float*)d_out;

    float* ws = (float*)d_ws;
    int*   idx    = (int*)ws;
    float* k_part = ws + 1024;
    float* q_part = k_part + (size_t)KS * B_ * NS_ * D_;
    float* v_part = q_part + (size_t)KSQ * B_ * D_;
    float* logits = v_part + (size_t)KS * B_ * NS_;
    float* v_red  = logits + B_ * NS_;

    prep_kernel   <<<8,   256, 0, stream>>>(mask, idx);
    kgemm_kernel  <<<320, 256, 0, stream>>>(hs, Wk, Wq, Wr, idx, k_part, v_part, q_part);
    logit_kernel  <<<128, 256, 0, stream>>>(k_part, q_part, v_part, bq, bk, br, logits, v_red);
    softmax_kernel<<<8,   128, 0, stream>>>(logits, v_red, out);
}

// Round 4
// 338.147 us; speedup vs baseline: 1.1709x; 1.0099x over previous
//
#include <hip/hip_runtime.h>
#include <hip/hip_bf16.h>

#define B_ 8
#define S_ 2048
#define H_ 4096
#define D_ 128
#define NS_ 128
#define KS 32            /* split-K for kgemm: KC = 128 h per block */
#define KC (H_ / KS)
#define KSQ 8            /* split-K for qproj */

typedef _Float16 half8 __attribute__((ext_vector_type(8)));
typedef float floatx4 __attribute__((ext_vector_type(4)));

// ---------------------------------------------------------------------------
// Workspace (byte offsets):
//   idx    : int[1024]             @ 0         (4 KB)
//   Bp_hi  : half8[65536]          @ 4096      (1 MB)  Wk in MFMA-frag order
//   Bp_lo  : half8[65536]          @ 1052672   (1 MB)
//   k_part : float[KS][B][NS][D]   @ 2101248   (16 MB)
//   q_part : float[KSQ][B][D]      @ +         (32 KB)
//   v_part : float[KS][B][NS]      @ +         (128 KB)
//   logits : float[B][NS], v_red : float[B][NS]
// every element written before read (ws poisoned 0xAA).
// Bp index: (((kc*2 + c)*2 + k0)*8 + dt)*64 + quad*16 + mrow
//   holds Wk[d = dt*16+mrow][h = kc*128 + c*64 + (k0*4+quad)*8 .. +8]
// so a wave's B-frag load is base + lane*16B — perfectly coalesced, L2-hot.
// ---------------------------------------------------------------------------

__device__ inline void cvt8(const float* x, half8* hi, half8* lo) {
    half8 h, l;
    #pragma unroll
    for (int j = 0; j < 8; ++j) {
        _Float16 hh = (_Float16)x[j];
        h[j] = hh;
        l[j] = (_Float16)(x[j] - (float)hh);
    }
    *hi = h; *lo = l;
}

__device__ inline floatx4 mfma16(half8 a, half8 b, floatx4 c) {
    return __builtin_amdgcn_mfma_f32_16x16x32_f16(a, b, c, 0, 0, 0);
}

// Kernel 1: blocks 0..7: extract per-row sorted positions of mask==1.
//           blocks 8..39: pre-convert+pack Wk into frag-ordered f16 hi/lo.
__global__ __launch_bounds__(256) void prep_kernel(
    const float* __restrict__ Wk, const int* __restrict__ mask,
    int* __restrict__ idx, half8* __restrict__ Bp_hi, half8* __restrict__ Bp_lo)
{
    int bid = blockIdx.x;
    int tid = threadIdx.x;
    if (bid >= 8) {
        // ---- Wk pack: one kc slice (128 d x 128 h) per block ----
        int kc = bid - 8;
        int d  = tid >> 1;          // 0..127
        int hh = tid & 1;           // chunk c
        const float* src = Wk + (size_t)d * H_ + kc * KC + hh * 64;
        int dt = d >> 4, mrow = d & 15;
        #pragma unroll
        for (int z = 0; z < 8; ++z) {
            float x[8];
            *(float4*)&x[0] = *(const float4*)(src + z * 8);
            *(float4*)&x[4] = *(const float4*)(src + z * 8 + 4);
            half8 hi, lo; cvt8(x, &hi, &lo);
            int k0 = z >> 2, quad = z & 3;
            int o = (((kc * 2 + hh) * 2 + k0) * 8 + dt) * 64 + quad * 16 + mrow;
            Bp_hi[o] = hi; Bp_lo[o] = lo;
        }
        return;
    }
    int b = bid;
    const int* mrow = mask + b * S_;
    __shared__ int wsum[4];
    int lane = tid & 63, wave = tid >> 6;
    int base = 0;
    for (int c = 0; c < S_ / 256; ++c) {
        int s = c * 256 + tid;
        int mv = mrow[s];
        unsigned long long bal = __ballot(mv != 0);
        int pre = __popcll(bal & ((1ull << lane) - 1ull));
        __syncthreads();
        if (lane == 0) wsum[wave] = __popcll(bal);
        __syncthreads();
        int woff = 0, tot = 0;
        #pragma unroll
        for (int w = 0; w < 4; ++w) { if (w < wave) woff += wsum[w]; tot += wsum[w]; }
        if (mv) idx[b * NS_ + base + woff + pre] = s;
        base += tot;
    }
}

// Kernel 2: blocks 0..255: gathered K-projection via f16x3 MFMA, split-K 32,
//           B-frags direct from pre-packed global (no LDS), exact-fp32
//           v-projection folded into A staging.
//           Blocks 256..319: q GEMV (split-K 8).
__global__ __launch_bounds__(256) void kgemm_kernel(
    const float* __restrict__ hs,
    const half8* __restrict__ Bp_hi, const half8* __restrict__ Bp_lo,
    const float* __restrict__ Wq, const float* __restrict__ Wr,
    const int* __restrict__ idx,
    float* __restrict__ k_part, float* __restrict__ v_part,
    float* __restrict__ q_part)
{
    __shared__ __align__(16) char smem[32768];
    int tid = threadIdx.x;
    int bid = blockIdx.x;

    if (bid >= 256) {
        // ---- q projection for the last selected token ----
        int qb = bid - 256;
        int b  = qb >> 3;
        int kc = qb & 7;
        float* hsrow = (float*)smem;            // 2 KB
        float* qred  = (float*)(smem + 2048);   // 512 B
        int ilast = idx[b * NS_ + NS_ - 1];
        const float* rp = hs + ((size_t)(b * S_ + ilast)) * H_ + kc * 512;
        if (tid < 128) ((float4*)hsrow)[tid] = ((const float4*)rp)[tid];
        __syncthreads();
        int d = tid & 127, half = tid >> 7;
        const float* wq = Wq + (size_t)d * H_ + kc * 512 + half * 256;
        const float* hh = hsrow + half * 256;
        float acc = 0.f;
        #pragma unroll 8
        for (int h = 0; h < 256; h += 4) {
            float4 w = *(const float4*)(wq + h);
            acc += hh[h] * w.x + hh[h + 1] * w.y + hh[h + 2] * w.z + hh[h + 3] * w.w;
        }
        if (half) qred[d] = acc;
        __syncthreads();
        if (!half) q_part[(kc * B_ + b) * D_ + d] = acc + qred[d];
        return;
    }

    int b  = bid >> 5;      // 0..7
    int kc = bid & 31;      // 0..31

    half8* AhS = (half8*)smem;                  // [8 kg][128 tok] : 16 KB
    half8* AlS = (half8*)(smem + 16384);

    int ia   = tid & 127;        // token for A-staging
    int half = tid >> 7;         // h-half (32 floats each)
    int row  = idx[b * NS_ + ia];
    const float* ap  = hs + ((size_t)(b * S_ + row)) * H_ + kc * KC + half * 32;
    const float* wrp = Wr + kc * KC + half * 32;

    int lane = tid & 63, w = tid >> 6;
    int quad = lane >> 4, mrow = lane & 15;
    int TB = (w >> 1) * 64;      // wave token base
    int DB = (w & 1) * 64;       // wave d base

    floatx4 acc[4][4];
    #pragma unroll
    for (int i = 0; i < 4; ++i)
        #pragma unroll
        for (int j = 0; j < 4; ++j) acc[i][j] = (floatx4){0.f, 0.f, 0.f, 0.f};
    float vacc = 0.f;

    #pragma unroll
    for (int c = 0; c < 2; ++c) {               // two 64-h chunks
        // ---- stage A (hi/lo f16) + exact v partial ----
        #pragma unroll
        for (int g = 0; g < 4; ++g) {
            float x[8], wv[8];
            *(float4*)&x[0]  = *(const float4*)(ap + c * 64 + g * 8);
            *(float4*)&x[4]  = *(const float4*)(ap + c * 64 + g * 8 + 4);
            *(float4*)&wv[0] = *(const float4*)(wrp + c * 64 + g * 8);
            *(float4*)&wv[4] = *(const float4*)(wrp + c * 64 + g * 8 + 4);
            #pragma unroll
            for (int j = 0; j < 8; ++j) vacc += x[j] * wv[j];
            half8 hi, lo; cvt8(x, &hi, &lo);
            AhS[(half * 4 + g) * 128 + ia] = hi;
            AlS[(half * 4 + g) * 128 + ia] = lo;
        }
        __syncthreads();

        // ---- MFMA: per k0, A-frags from LDS, B-frags direct from global ----
        #pragma unroll
        for (int k0 = 0; k0 < 2; ++k0) {
            int kb = (k0 * 4 + quad) * 128;
            int boff = (((kc * 2 + c) * 2 + k0) * 8 + (DB >> 4)) * 64 + lane;
            half8 ah[4], al[4], bh[4], bl[4];
            #pragma unroll
            for (int i = 0; i < 4; ++i) {
                bh[i] = Bp_hi[boff + i * 64];
                bl[i] = Bp_lo[boff + i * 64];
                ah[i] = AhS[kb + TB + i * 16 + mrow];
                al[i] = AlS[kb + TB + i * 16 + mrow];
            }
            #pragma unroll
            for (int mt = 0; mt < 4; ++mt)
                #pragma unroll
                for (int nt = 0; nt < 4; ++nt) {
                    acc[mt][nt] = mfma16(ah[mt], bh[nt], acc[mt][nt]);
                    acc[mt][nt] = mfma16(ah[mt], bl[nt], acc[mt][nt]);
                    acc[mt][nt] = mfma16(al[mt], bh[nt], acc[mt][nt]);
                }
        }
        __syncthreads();
    }

    // ---- epilogue: write k_part in [tok][d] layout per C/D mapping ----
    float* kp = k_part + (size_t)(kc * B_ + b) * NS_ * D_;
    #pragma unroll
    for (int mt = 0; mt < 4; ++mt)
        #pragma unroll
        for (int nt = 0; nt < 4; ++nt)
            #pragma unroll
            for (int r = 0; r < 4; ++r) {
                int tok = TB + mt * 16 + quad * 4 + r;
                int d   = DB + nt * 16 + mrow;
                kp[tok * D_ + d] = acc[mt][nt][r];
            }

    // ---- v reduce (reuse smem; frag reads are behind the last barrier) ----
    float* vb = (float*)smem;
    vb[half * 128 + ia] = vacc;
    __syncthreads();
    if (tid < 128) v_part[(kc * B_ + b) * NS_ + tid] = vb[tid] + vb[128 + tid];
}

// Kernel 3: per (b, 8-token chunk): reduce q/k/v partials, RoPE, logits.
__global__ __launch_bounds__(256) void logit_kernel(
    const float* __restrict__ k_part, const float* __restrict__ q_part,
    const float* __restrict__ v_part,
    const float* __restrict__ bq, const float* __restrict__ bk,
    const float* __restrict__ br,
    float* __restrict__ logits, float* __restrict__ v_red)
{
    int b  = blockIdx.x >> 4;
    int tc = blockIdx.x & 15;
    int tid = threadIdx.x;
    __shared__ float qtmp[2][D_];
    __shared__ float qr[D_];
    __shared__ float lred[8][32];

    {
        int d = tid & 127, hf = tid >> 7;
        float qv = hf ? 0.f : bq[d];
        #pragma unroll
        for (int kc = 0; kc < 4; ++kc) qv += q_part[((hf * 4 + kc) * B_ + b) * D_ + d];
        qtmp[hf][d] = qv;
    }
    int vt = tid >> 5, vkc = tid & 31;
    float vv = v_part[(vkc * B_ + b) * NS_ + tc * 8 + vt];
    __syncthreads();

    if (tid < 128) {
        int i = tid >> 1;
        float x0 = qtmp[0][2 * i] + qtmp[1][2 * i];
        float x1 = qtmp[0][2 * i + 1] + qtmp[1][2 * i + 1];
        float fr = 1.0f / powf(10000.0f, (float)(2 * i) / 128.0f);
        float s, c; sincosf(127.0f * fr, &s, &c);
        qr[tid] = (tid & 1) ? (x0 * s + x1 * c) : (x0 * c - x1 * s);
    }
    lred[vt][vkc] = vv;
    __syncthreads();
    if (tid < 8) {
        float s = br[0];
        #pragma unroll
        for (int j = 0; j < 32; ++j) s += lred[tid][j];
        v_red[b * NS_ + tc * 8 + tid] = s;
    }

    int tok = tid >> 5, q4 = tid & 31;
    int tg  = tc * 8 + tok;
    float4 kv = make_float4(0.f, 0.f, 0.f, 0.f);
    #pragma unroll 8
    for (int kc = 0; kc < KS; ++kc) {
        float4 x = *(const float4*)(k_part + ((size_t)(kc * B_ + b) * NS_ + tg) * D_ + q4 * 4);
        kv.x += x.x; kv.y += x.y; kv.z += x.z; kv.w += x.w;
    }
    kv.x += bk[4 * q4 + 0]; kv.y += bk[4 * q4 + 1];
    kv.z += bk[4 * q4 + 2]; kv.w += bk[4 * q4 + 3];
    float fr0 = 1.0f / powf(10000.0f, (float)(4 * q4) / 128.0f);
    float fr1 = 1.0f / powf(10000.0f, (float)(4 * q4 + 2) / 128.0f);
    float s0, c0, s1, c1;
    sincosf((float)tg * fr0, &s0, &c0);
    sincosf((float)tg * fr1, &s1, &c1);
    float k0 = kv.x * c0 - kv.y * s0;
    float k1 = kv.x * s0 + kv.y * c0;
    float k2 = kv.z * c1 - kv.w * s1;
    float k3 = kv.z * s1 + kv.w * c1;
    float part = k0 * qr[4 * q4] + k1 * qr[4 * q4 + 1]
               + k2 * qr[4 * q4 + 2] + k3 * qr[4 * q4 + 3];
    __syncthreads();
    lred[tok][q4] = part;
    __syncthreads();
    if (tid < 8) {
        float s = 0.f;
        #pragma unroll
        for (int j = 0; j < 32; ++j) s += lred[tid][j];
        logits[b * NS_ + tc * 8 + tid] = s * 0.08838834764831845f;
    }
}

// Kernel 4: per-b softmax + first-difference + outputs.
__global__ __launch_bounds__(128) void softmax_kernel(
    const float* __restrict__ logits, const float* __restrict__ v_red,
    float* __restrict__ out)
{
    int b = blockIdx.x;
    int t = threadIdx.x;
    __shared__ float red[128];
    __shared__ float vsh[128];

    float logit = logits[b * NS_ + t];
    vsh[t] = v_red[b * NS_ + t];
    red[t] = logit;
    __syncthreads();
    float sr = (t == 0) ? vsh[0] : vsh[t] - vsh[t - 1];
    #pragma unroll
    for (int off = 64; off > 0; off >>= 1) {
        if (t < off) red[t] = fmaxf(red[t], red[t + off]);
        __syncthreads();
    }
    float mx = red[0];
    __syncthreads();
    float e = expf(logit - mx);
    red[t] = e;
    __syncthreads();
    #pragma unroll
    for (int off = 64; off > 0; off >>= 1) {
        if (t < off) red[t] += red[t + off];
        __syncthreads();
    }
    float attn = e / red[0];
    out[b * NS_ + t] = sr * attn;
    __syncthreads();
    red[t] = attn * sr;
    __syncthreads();
    #pragma unroll
    for (int off = 64; off > 0; off >>= 1) {
        if (t < off) red[t] += red[t + off];
        __syncthreads();
    }
    if (t == 0) out[B_ * NS_ + b] = red[0];
}

extern "C" void kernel_launch(void* const* d_in, const int* in_sizes, int n_in,
                              void* d_out, int out_size, void* d_ws, size_t ws_size,
                              hipStream_t stream) {
    const float* hs   = (const float*)d_in[0];
    const int*   mask = (const int*)d_in[1];
    const float* Wq = (const float*)d_in[3];
    const float* bq = (const float*)d_in[4];
    const float* Wk = (const float*)d_in[5];
    const float* bk = (const float*)d_in[6];
    const float* Wr = (const float*)d_in[7];
    const float* br = (const float*)d_in[8];
    float* out = (float*)d_out;

    char* wsb = (char*)d_ws;
    int*   idx    = (int*)wsb;                              // 4 KB
    half8* Bp_hi  = (half8*)(wsb + 4096);                   // 1 MB
    half8* Bp_lo  = (half8*)(wsb + 4096 + 1048576);         // 1 MB
    float* k_part = (float*)(wsb + 4096 + 2097152);         // 16 MB
    float* q_part = k_part + (size_t)KS * B_ * NS_ * D_;
    float* v_part = q_part + (size_t)KSQ * B_ * D_;
    float* logits = v_part + (size_t)KS * B_ * NS_;
    float* v_red  = logits + B_ * NS_;

    prep_kernel   <<<40,  256, 0, stream>>>(Wk, mask, idx, Bp_hi, Bp_lo);
    kgemm_kernel  <<<320, 256, 0, stream>>>(hs, Bp_hi, Bp_lo, Wq, Wr, idx, k_part, v_part, q_part);
    logit_kernel  <<<128, 256, 0, stream>>>(k_part, q_part, v_part, bq, bk, br, logits, v_red);
    softmax_kernel<<<8,   128, 0, stream>>>(logits, v_red, out);
}